// Round 3
// baseline (971.577 us; speedup 1.0000x reference)
//
#include <hip/hip_runtime.h>
#include <cmath>

// Problem constants
constexpr int Bn   = 64;
constexpr int Sn   = 8192;
constexpr int DDEC = 128;
constexpr int DENC = 128;
constexpr int Fn   = 16;
constexpr int Un   = 128;
constexpr int UC   = 64;   // u register-block per thread (64 accumulator VGPRs)

__device__ __forceinline__ float fast_tanh(float x) {
    // tanh(x) = sign(x) * (1 - 2/(exp(2|x|)+1)); exp overflow -> rcp(inf)=0 -> t=1 (correct saturation)
    float ax = fabsf(x);
    float e  = __expf(2.0f * ax);
    float t  = 1.0f - 2.0f * __builtin_amdgcn_rcpf(e + 1.0f);
    return copysignf(t, x);
}

// Setup: qq[b][u] = dec[b]@W1[:,u] + W1_b[u] + W2_b[u]   (W2 bias folded in)
//        w2t[u][d] = W2[d][u]  (u-major so hot loop reads contiguous wave-uniform rows -> s_load_dwordx8)
__global__ void setup_kernel(const float* __restrict__ dec,
                             const float* __restrict__ W1,
                             const float* __restrict__ W1b,
                             const float* __restrict__ W2,
                             const float* __restrict__ W2b,
                             float* __restrict__ qq,
                             float* __restrict__ w2t) {
    int u = threadIdx.x;           // 128 threads
    int blk = blockIdx.x;
    if (blk < Bn) {
        int b = blk;
        float acc = W1b[u] + W2b[u];
        #pragma unroll 8
        for (int d = 0; d < DDEC; ++d)
            acc = fmaf(dec[b * DDEC + d], W1[d * Un + u], acc);
        qq[b * Un + u] = acc;
    } else {
        for (int d = 0; d < DENC; ++d)
            w2t[u * DENC + d] = W2[d * Un + u];
    }
}

// Main: per thread = one (b,s) row, u-register-blocked.
// Round-2 lesson: holding the enc ROW in registers gets defeated by load
// sinking (VGPR=72, row re-read 128x from L1 -> VMEM-bound, 30% VALUBusy).
// Here the long-lived state is 64 ACCUMULATORS k[UC] (cannot be sunk), the
// enc row is streamed in 8-float chunks (read only Un/UC = 2x total), and
// W2t rows are wave-uniform scalar loads consumed straight from SGPRs by
// v_fma_f32 (1 sgpr operand allowed). VMEM per wave: 4096 -> 64 loads.
__global__ __launch_bounds__(256, 4)
void score_kernel(const float* __restrict__ enc,    // [B,S,DENC]
                  const float* __restrict__ mask,   // [B,S]
                  const float* __restrict__ qq,     // [B,U]
                  const float* __restrict__ w2t,    // [U,DENC] u-major
                  const float* __restrict__ V,      // [U]
                  const float* __restrict__ Vb,     // [1]
                  float* __restrict__ logits) {     // [B,S]
    int row = blockIdx.x * 256 + threadIdx.x;       // 0..B*S-1
    int b = row >> 13;                              // S = 8192

    const float* erow = enc + (size_t)row * DENC;
    const float* qrow = qq + b * Un;                // wave-uniform
    float score = Vb[0];

    #pragma unroll 1
    for (int uc = 0; uc < Un; uc += UC) {
        float k[UC];
        #pragma unroll
        for (int i = 0; i < UC; ++i) k[i] = qrow[uc + i];   // scalar loads

        #pragma unroll 1
        for (int dc = 0; dc < DENC; dc += 8) {
            float4 e0 = *(const float4*)(erow + dc);
            float4 e1 = *(const float4*)(erow + dc + 4);
            #pragma unroll
            for (int i = 0; i < UC; ++i) {
                const float* w = w2t + (uc + i) * DENC + dc;  // wave-uniform -> s_load_dwordx8
                k[i] = fmaf(e0.x, w[0], k[i]);
                k[i] = fmaf(e0.y, w[1], k[i]);
                k[i] = fmaf(e0.z, w[2], k[i]);
                k[i] = fmaf(e0.w, w[3], k[i]);
                k[i] = fmaf(e1.x, w[4], k[i]);
                k[i] = fmaf(e1.y, w[5], k[i]);
                k[i] = fmaf(e1.z, w[6], k[i]);
                k[i] = fmaf(e1.w, w[7], k[i]);
            }
        }

        #pragma unroll
        for (int i = 0; i < UC; ++i)
            score = fmaf(fast_tanh(k[i]), V[uc + i], score);
    }

    float logit = 10.0f * fast_tanh(score) - mask[row] * 1e9f;
    logits[row] = logit;
}

// Softmax + argmax + gather, one block per b.
__global__ __launch_bounds__(256)
void softmax_kernel(const float* __restrict__ logits,  // [B,S]
                    const float* __restrict__ enc_in,  // [B,S,F]
                    float* __restrict__ probs,         // [B,S]
                    float* __restrict__ out_idx,       // [B] (written as float)
                    float* __restrict__ out_gath) {    // [B,F]
    int b = blockIdx.x, tid = threadIdx.x;
    __shared__ float smax[256];
    __shared__ int   sidx[256];
    __shared__ float ssum[256];

    const float* lrow = logits + (size_t)b * Sn;
    float* prow = probs + (size_t)b * Sn;

    // Pass 1: max + first-occurrence argmax
    float bestv = -INFINITY; int besti = 0x7fffffff;
    for (int s = tid; s < Sn; s += 256) {
        float v = lrow[s];
        if (v > bestv) { bestv = v; besti = s; }
    }
    smax[tid] = bestv; sidx[tid] = besti;
    __syncthreads();
    for (int off = 128; off > 0; off >>= 1) {
        if (tid < off) {
            float ov = smax[tid + off]; int oi = sidx[tid + off];
            if (ov > smax[tid] || (ov == smax[tid] && oi < sidx[tid])) {
                smax[tid] = ov; sidx[tid] = oi;
            }
        }
        __syncthreads();
    }
    float M = smax[0]; int I = sidx[0];

    // Pass 2: exp into probs + partial sums
    float psum = 0.0f;
    for (int s = tid; s < Sn; s += 256) {
        float ev = __expf(lrow[s] - M);
        prow[s] = ev;
        psum += ev;
    }
    ssum[tid] = psum;
    __syncthreads();
    for (int off = 128; off > 0; off >>= 1) {
        if (tid < off) ssum[tid] += ssum[tid + off];
        __syncthreads();
    }
    float inv = 1.0f / ssum[0];

    // Pass 3: scale stored exp
    for (int s = tid; s < Sn; s += 256)
        prow[s] *= inv;

    // Index (numeric value as float32) + gather
    if (tid == 0) out_idx[b] = (float)I;
    if (tid < Fn) out_gath[b * Fn + tid] = enc_in[((size_t)b * Sn + I) * Fn + tid];
}

extern "C" void kernel_launch(void* const* d_in, const int* in_sizes, int n_in,
                              void* d_out, int out_size, void* d_ws, size_t ws_size,
                              hipStream_t stream) {
    const float* dec    = (const float*)d_in[0];  // [B,1,DDEC]
    const float* enc_in = (const float*)d_in[1];  // [B,S,F]
    const float* enc    = (const float*)d_in[2];  // [B,S,DENC]
    const float* mask   = (const float*)d_in[3];  // [B,S]
    const float* W1     = (const float*)d_in[4];  // [DDEC,U]
    const float* W1b    = (const float*)d_in[5];  // [U]
    const float* W2     = (const float*)d_in[6];  // [DENC,U]
    const float* W2b    = (const float*)d_in[7];  // [U]
    const float* V      = (const float*)d_in[8];  // [U,1]
    const float* Vb     = (const float*)d_in[9];  // [1]

    float* qq  = (float*)d_ws;          // B*U floats
    float* w2t = qq + Bn * Un;          // U*DENC floats

    float* logits = (float*)d_out;                  // [B,S]
    float* probs  = logits + (size_t)Bn * Sn;       // [B,S]
    float* oidx   = probs + (size_t)Bn * Sn;        // [B]
    float* ogath  = oidx + Bn;                      // [B,F]

    setup_kernel<<<Bn + 1, 128, 0, stream>>>(dec, W1, W1b, W2, W2b, qq, w2t);
    score_kernel<<<(Bn * Sn) / 256, 256, 0, stream>>>(enc, mask, qq, w2t, V, Vb, logits);
    softmax_kernel<<<Bn, 256, 0, stream>>>(logits, enc_in, probs, oidx, ogath);
}